// Round 17
// baseline (469.156 us; speedup 1.0000x reference)
//
#include <hip/hip_runtime.h>
#include <stdint.h>

typedef unsigned short u16;
typedef __attribute__((ext_vector_type(8))) short  s16x8;
typedef __attribute__((ext_vector_type(8))) __bf16 b16x8;
typedef __attribute__((ext_vector_type(4))) float  f32x4;

__device__ __forceinline__ float bf2f(u16 u){
  union { unsigned int ui; float f; } v; v.ui = ((unsigned int)u) << 16; return v.f;
}
__device__ __forceinline__ u16 f2bf(float f){
  union { float f; unsigned int ui; } v; v.f = f;
  unsigned int u = v.ui;
  u += 0x7FFFu + ((u >> 16) & 1u);      // RNE
  return (u16)(u >> 16);
}
__device__ __forceinline__ f32x4 mfma16(s16x8 a, s16x8 b, f32x4 c){
  return __builtin_amdgcn_mfma_f32_16x16x32_bf16(
      __builtin_bit_cast(b16x8, a), __builtin_bit_cast(b16x8, b), c, 0, 0, 0);
}
__device__ __forceinline__ void gload_lds16(const u16* g, u16* l){
  __builtin_amdgcn_global_load_lds(
      (const __attribute__((address_space(1))) unsigned int*)(g),
      (__attribute__((address_space(3))) unsigned int*)(l), 16, 0, 0);
}
__device__ __forceinline__ uint32_t cvt_pk_bf16(float lo, float hi){
  uint32_t r;
  asm("v_cvt_pk_bf16_f32 %0, %1, %2" : "=v"(r) : "v"(lo), "v"(hi));
  return r;
}

// ---------------- elementwise cast f32 -> bf16 (8 elems/thread) ----------------
__global__ __launch_bounds__(256) void cast_f32_bf16(const float* __restrict__ in,
                                                     u16* __restrict__ out, int n8){
  int i = blockIdx.x * 256 + threadIdx.x;
  if (i >= n8) return;
  const f32x4* p = (const f32x4*)(in + (size_t)i * 8);
  f32x4 a = p[0], c = p[1];
  s16x8 o;
#pragma unroll
  for (int j = 0; j < 4; j++){ o[j] = (short)f2bf(a[j]); o[j+4] = (short)f2bf(c[j]); }
  *(s16x8*)(out + (size_t)i * 8) = o;
}

// ---------------- transpose + cast: in f32 [R][C] -> out bf16 [C][R] ----------------
__global__ __launch_bounds__(256) void tcast(const float* __restrict__ in,
                                             u16* __restrict__ out, int R, int C){
  __shared__ float tile[32][33];
  int c0 = blockIdx.x * 32, r0 = blockIdx.y * 32;
  int tc = threadIdx.x & 31, tr = threadIdx.x >> 5;
#pragma unroll
  for (int p = 0; p < 4; p++)
    tile[tr + 8*p][tc] = in[(size_t)(r0 + tr + 8*p) * C + c0 + tc];
  __syncthreads();
  int rr = threadIdx.x & 31, cc = threadIdx.x >> 5;
#pragma unroll
  for (int p = 0; p < 4; p++)
    out[(size_t)(c0 + cc + 8*p) * R + r0 + rr] = f2bf(tile[rr][cc + 8*p]);
}

// ---------------- GEMM v2: global_load_lds staging + chunk^row swizzle ----------------
// C[M,N] = A[M,1024] * Bt[N,1024]^T (bf16 MFMA), 128x128 tile, BK=32, dbuf LDS.
// Staging: linear LDS dest (wave-uniform base + lane*16), source pre-swizzled
// chunk' = chunk ^ (row&3); fragment reads apply the same XOR -> b128 conflict floor.
// mode 0: n<1024 -> Q; <2048 -> K; else V   ([bh][i][64])
// mode 1: + b_r -> R rows at stride 4224 (caller pre-offsets base past 128-row pad)
__global__ __launch_bounds__(256) void gemm_bt(const u16* __restrict__ A,
                                               const u16* __restrict__ Bt,
                                               int mode,
                                               u16* __restrict__ Qo, u16* __restrict__ Ko,
                                               u16* __restrict__ Vo, u16* __restrict__ Ro,
                                               const float* __restrict__ brp){
  __shared__ __align__(16) u16 lsA[2][128 * 32];
  __shared__ __align__(16) u16 lsB[2][128 * 32];
  int m0 = blockIdx.y * 128, n0 = blockIdx.x * 128;
  int t = threadIdx.x, wid = t >> 6, lane = t & 63;
  int lrow = lane & 15, lk = lane >> 4;
  int wr = wid >> 1, wc = wid & 1;

  f32x4 acc[4][4];
#pragma unroll
  for (int i = 0; i < 4; i++)
#pragma unroll
    for (int j = 0; j < 4; j++) acc[i][j] = (f32x4){0.f, 0.f, 0.f, 0.f};

  // per-thread staging source bases (row/chunk fixed across K-tiles)
  const u16* aSrc[2];
  const u16* bSrc[2];
  u16* aDst[2];
  u16* bDst[2];
#pragma unroll
  for (int p = 0; p < 2; p++){
    int c = p * 256 + t;
    int row = c >> 2, ch = c & 3;
    int sch = ch ^ (row & 3);
    aSrc[p] = A  + (size_t)(m0 + row) * 1024 + sch * 8;
    bSrc[p] = Bt + (size_t)(n0 + row) * 1024 + sch * 8;
    aDst[p] = (u16*)lsA[0] + (p * 256 + wid * 64) * 8;   // +lane*8 added by HW
    bDst[p] = (u16*)lsB[0] + (p * 256 + wid * 64) * 8;
  }
  const size_t bufOff = 128 * 32;   // u16 elems between buf0 and buf1

  // prologue: stage K-tile 0 into buf 0
#pragma unroll
  for (int p = 0; p < 2; p++){
    gload_lds16(aSrc[p], aDst[p]);
    gload_lds16(bSrc[p], bDst[p]);
  }
  __syncthreads();

  int buf = 0;
  for (int kt = 0; kt < 32; kt++){
    // stage K-tile kt+1 into other buffer (async; drained by end-of-iter barrier)
    if (kt < 31){
      int k0 = (kt + 1) * 32;
      size_t od = (buf ^ 1) ? bufOff : 0;
#pragma unroll
      for (int p = 0; p < 2; p++){
        gload_lds16(aSrc[p] + k0, aDst[p] + od);
        gload_lds16(bSrc[p] + k0, bDst[p] + od);
      }
    }
    // compute from current buffer (swizzled fragment reads)
    const u16* la = lsA[buf];
    const u16* lb = lsB[buf];
    s16x8 af[4], bfr[4];
#pragma unroll
    for (int i = 0; i < 4; i++){
      int row = wr * 64 + i * 16 + lrow;
      af[i] = *(const s16x8*)(la + row * 32 + (lk ^ (row & 3)) * 8);
    }
#pragma unroll
    for (int j = 0; j < 4; j++){
      int row = wc * 64 + j * 16 + lrow;
      bfr[j] = *(const s16x8*)(lb + row * 32 + (lk ^ (row & 3)) * 8);
    }
#pragma unroll
    for (int i = 0; i < 4; i++)
#pragma unroll
      for (int j = 0; j < 4; j++)
        acc[i][j] = mfma16(af[i], bfr[j], acc[i][j]);
    __syncthreads();
    buf ^= 1;
  }

#pragma unroll
  for (int i = 0; i < 4; i++)
#pragma unroll
    for (int j = 0; j < 4; j++){
      int mbase = m0 + wr * 64 + i * 16 + lk * 4;
      int ncol  = n0 + wc * 64 + j * 16 + lrow;
#pragma unroll
      for (int r = 0; r < 4; r++){
        int m = mbase + r;
        float val = acc[i][j][r];
        if (mode == 0){
          int sel = ncol >> 10;
          int hd = ncol & 1023;
          int h = hd >> 6, dh = hd & 63;
          int b = m & 3, iq = m >> 2;
          size_t o = ((size_t)(b * 16 + h) * 2048 + iq) * 64 + dh;
          u16 vb = f2bf(val);
          if (sel == 0) Qo[o] = vb; else if (sel == 1) Ko[o] = vb; else Vo[o] = vb;
        } else {
          int h = ncol >> 6, dh = ncol & 63;
          Ro[((size_t)h * 4224 + m) * 64 + dh] = f2bf(val + brp[ncol]);
        }
      }
    }
}

// ---------------- V [bh][2048][64] -> VT [bh][64][2048] (bf16) ----------------
__global__ __launch_bounds__(256) void transpose_v(const u16* __restrict__ V,
                                                   u16* __restrict__ VT){
  __shared__ u16 tile[64][65];
  int bh = blockIdx.y, i0 = blockIdx.x * 64;
  const u16* src = V + ((size_t)bh * 2048 + i0) * 64;
  int t = threadIdx.x;
#pragma unroll
  for (int p = 0; p < 2; p++){
    int idx = (p * 256 + t) * 8;
    int row = idx >> 6, col = idx & 63;
    s16x8 v = *(const s16x8*)(src + idx);
#pragma unroll
    for (int e = 0; e < 8; e++) tile[row][col + e] = (u16)v[e];
  }
  __syncthreads();
  u16* dst = VT + (size_t)bh * 64 * 2048 + i0;
#pragma unroll
  for (int p = 0; p < 2; p++){
    int idx = (p * 256 + t) * 8;
    int dh = idx >> 6, ii = idx & 63;
    s16x8 o;
#pragma unroll
    for (int e = 0; e < 8; e++) o[e] = (short)tile[ii + e][dh];
    *(s16x8*)(dst + (size_t)dh * 2048 + ii) = o;
  }
}

// ---------------- fused rel-shift flash attention v17 == v16 (best measured; unchanged) ----------------
// grid 2048 (XCD-swizzled), 256 thr = 4 waves, wave = 16 q rows, KVBLK = 64.
// LDS 37888 -> 40960 granule; x4 = 163840 -> 4 blocks/CU (occ 46%, VGPR 64).
// Rolling 2-deep R loads (16 VGPR peak), single-buffer K/V with consolidated refill window.
// BDs: d<=0 -> qb0 . r[d+2047]; d==1 -> 0; d>=2 -> qb1 . r[d-2]   (d = k - q)
__global__ __launch_bounds__(256, 4) void attn17_kernel(const u16* __restrict__ Qm,
                                                        const u16* __restrict__ Km,
                                                        const u16* __restrict__ Vt,
                                                        const u16* __restrict__ Rm,
                                                        const float* __restrict__ bq,
                                                        const float* __restrict__ bk,
                                                        float* __restrict__ Out){
  __shared__ __align__(16) u16   Kt[64 * 64];
  __shared__ __align__(16) u16   Vs[64 * 64];
  __shared__ __align__(16) float Gs[4][16 * 84];   // per-wave f32 G; P (stride-88 u16) aliases

  int lin = blockIdx.x;
  int xcd = lin & 7, j = lin >> 3;
  int hb = xcd * 8 + (j >> 5);
  int bx = j & 31;
  int h = hb & 15, b = hb >> 4;

  const int wid = threadIdx.x >> 6, lane = threadIdx.x & 63;
  const int lrow = lane & 15, lk = lane >> 4;
  const int q0 = bx * 64 + wid * 16;
  const size_t bh = (size_t)b * 16 + h;
  const u16* Qp = Qm + bh * 2048 * 64;
  const u16* Kp = Km + bh * 2048 * 64;
  const u16* Vp = Vt + bh * 64 * 2048;
  const u16* Rp = Rm + ((size_t)h * 4224 + 128) * 64;   // real row 0
  float* Gw = Gs[wid];
  u16*   Pw = (u16*)Gs[wid];

  const float cs = 0.125f * 1.44269504088896f;   // (1/sqrt(64))*log2(e), folded into q frags

  s16x8 qa[2], qb0[2], qb1[2];
  {
    const float* bqp = bq + h * 64;
    const float* bkp = bk + h * 64;
    int r1 = q0 + lrow + 1; if (r1 > 2047) r1 = 2047;   // q=2047 shifted row never selected
#pragma unroll
    for (int d = 0; d < 2; d++){
      int doff = d * 32 + lk * 8;
      s16x8 raw  = *(const s16x8*)(Qp + (size_t)(q0 + lrow) * 64 + doff);
      s16x8 raw1 = *(const s16x8*)(Qp + (size_t)r1 * 64 + doff);
      s16x8 a, c0, c1;
#pragma unroll
      for (int jj = 0; jj < 8; jj++){
        float qv = bf2f((u16)raw[jj]);
        float q1 = bf2f((u16)raw1[jj]);
        a[jj]  = (short)f2bf(cs * (qv + bqp[doff + jj]));
        c0[jj] = (short)f2bf(cs * (qv + bkp[doff + jj]));
        c1[jj] = (short)f2bf(cs * (q1 + bkp[doff + jj]));
      }
      qa[d] = a; qb0[d] = c0; qb1[d] = c1;
    }
  }

  const u16* r1p = Rp + (size_t)(2032 - q0 + lrow) * 64 + lk * 8;
  const u16* r2p = r1p - (size_t)2049 * 64;

  float m = -3.0e38f, l = 0.f;
  f32x4 Oc[4];
#pragma unroll
  for (int f = 0; f < 4; f++) Oc[f] = (f32x4){0.f, 0.f, 0.f, 0.f};

  const int wbase = 15 - lrow + 4 * lk;
  const int dl0   = 4 * lk - lrow;

  // prologue: stage K+V tile 0
#pragma unroll
  for (int i = 0; i < 2; i++){
    int g = wid * 2 + i;
    int row = g * 8 + (lane >> 3);
    int sch = (lane & 7) ^ (row & 7);
    gload_lds16(Kp + (size_t)row * 64 + sch * 8, Kt + g * 512);
    gload_lds16(Vp + (size_t)row * 2048 + sch * 8, Vs + g * 512);
  }
  __syncthreads();

  for (int t = 0; t < 32; t++){
    const int k0 = t * 64;
    const int d0 = k0 - q0;
    const bool n1 = (d0 <= 15);
    const bool n2 = (d0 >= -61);
    const bool pure = (d0 <= -63) | (d0 >= 17);
    const int dlane = d0 + dl0;

    // first 2 R window rows issued early (S-phase covers their latency)
    const u16* rp = n1 ? r1p : r2p;
    s16x8 ra[2][2];
    ra[0][0] = *(const s16x8*)(rp);
    ra[0][1] = *(const s16x8*)(rp + 32);
    ra[1][0] = *(const s16x8*)(rp + 1024);
    ra[1][1] = *(const s16x8*)(rp + 1024 + 32);

    // S^T = mfma(K, qa)
    f32x4 S[4];
    __builtin_amdgcn_s_setprio(1);
#pragma unroll
    for (int kf = 0; kf < 4; kf++){
      f32x4 acc = (f32x4){0.f, 0.f, 0.f, 0.f};
#pragma unroll
      for (int d = 0; d < 2; d++){
        int row = kf * 16 + lrow;
        int ch = (d * 4 + lk) ^ (row & 7);
        s16x8 kfr = *(const s16x8*)(Kt + row * 64 + ch * 8);
        acc = mfma16(kfr, qa[d], acc);
      }
      S[kf] = acc;
    }
    __builtin_amdgcn_s_setprio(0);

    // BD primary pass: rolling 2-deep loads
    {
      const s16x8* qs = n1 ? qb0 : qb1;
#pragma unroll
      for (int wf = 0; wf < 5; wf++){
        s16x8 c0 = ra[wf & 1][0], c1 = ra[wf & 1][1];
        if (wf < 3){
          ra[wf & 1][0] = *(const s16x8*)(rp + (wf + 2) * 1024);
          ra[wf & 1][1] = *(const s16x8*)(rp + (wf + 2) * 1024 + 32);
        }
        f32x4 g = (f32x4){0.f, 0.f, 0.f, 0.f};
        g = mfma16(c0, qs[0], g);
        g = mfma16(c1, qs[1], g);
        *(f32x4*)(Gw + lrow * 84 + wf * 16 + 4 * lk) = g;
      }
      const float* gp = Gw + lrow * 84 + wbase;
      if (pure){
#pragma unroll
        for (int kf = 0; kf < 4; kf++)
#pragma unroll
          for (int r = 0; r < 4; r++) S[kf][r] += gp[kf * 16 + r];
      } else if (n1){
#pragma unroll
        for (int kf = 0; kf < 4; kf++)
#pragma unroll
          for (int r = 0; r < 4; r++){
            float g = gp[kf * 16 + r];
            S[kf][r] += (dlane + kf * 16 + r <= 0) ? g : 0.f;
          }
      } else {
#pragma unroll
        for (int kf = 0; kf < 4; kf++)
#pragma unroll
          for (int r = 0; r < 4; r++){
            float g = gp[kf * 16 + r];
            S[kf][r] += (dlane + kf * 16 + r >= 2) ? g : 0.f;
          }
      }
    }
    // BD secondary pass (near-diagonal tiles only)
    if (n1 && n2){
      ra[0][0] = *(const s16x8*)(r2p);
      ra[0][1] = *(const s16x8*)(r2p + 32);
      ra[1][0] = *(const s16x8*)(r2p + 1024);
      ra[1][1] = *(const s16x8*)(r2p + 1024 + 32);
#pragma unroll
      for (int wf = 0; wf < 5; wf++){
        s16x8 c0 = ra[wf & 1][0], c1 = ra[wf & 1][1];
        if (wf < 3){
          ra[wf & 1][0] = *(const s16x8*)(r2p + (wf + 2) * 1024);
          ra[wf & 1][1] = *(const s16x8*)(r2p + (wf + 2) * 1024 + 32);
        }
        f32x4 g = (f32x4){0.f, 0.f, 0.f, 0.f};
        g = mfma16(c0, qb1[0], g);
        g = mfma16(c1, qb1[1], g);
        *(f32x4*)(Gw + lrow * 84 + wf * 16 + 4 * lk) = g;
      }
      const float* gp = Gw + lrow * 84 + wbase;
#pragma unroll
      for (int kf = 0; kf < 4; kf++)
#pragma unroll
        for (int r = 0; r < 4; r++){
          float g = gp[kf * 16 + r];
          S[kf][r] += (dlane + kf * 16 + r >= 2) ? g : 0.f;
        }
    }

    // softmax (q lane-local; exp2 domain, defer-max, tree reductions)
    float e0 = fmaxf(fmaxf(S[0][0], S[0][1]), fmaxf(S[0][2], S[0][3]));
    float e1 = fmaxf(fmaxf(S[1][0], S[1][1]), fmaxf(S[1][2], S[1][3]));
    float e2 = fmaxf(fmaxf(S[2][0], S[2][1]), fmaxf(S[2][2], S[2][3]));
    float e3 = fmaxf(fmaxf(S[3][0], S[3][1]), fmaxf(S[3][2], S[3][3]));
    float tmax = fmaxf(fmaxf(e0, e1), fmaxf(e2, e3));
    tmax = fmaxf(tmax, __shfl_xor(tmax, 16, 64));
    tmax = fmaxf(tmax, __shfl_xor(tmax, 32, 64));
    if (tmax > m + 11.5f){
      float al = exp2f(m - tmax);
      l *= al;
#pragma unroll
      for (int f = 0; f < 4; f++) Oc[f] *= al;
      m = tmax;
    }
#pragma unroll
    for (int kf = 0; kf < 4; kf++)
#pragma unroll
      for (int r = 0; r < 4; r++)
        S[kf][r] = exp2f(S[kf][r] - m);
    float s0 = (S[0][0] + S[0][1]) + (S[0][2] + S[0][3]);
    float s1 = (S[1][0] + S[1][1]) + (S[1][2] + S[1][3]);
    float s2 = (S[2][0] + S[2][1]) + (S[2][2] + S[2][3]);
    float s3 = (S[3][0] + S[3][1]) + (S[3][2] + S[3][3]);
    float sum = (s0 + s1) + (s2 + s3);
    sum += __shfl_xor(sum, 16, 64);
    sum += __shfl_xor(sum, 32, 64);
    l += sum;

    // P pack -> LDS [q][k] stride 88 halves
#pragma unroll
    for (int kf = 0; kf < 4; kf++){
      uint32_t u0 = cvt_pk_bf16(S[kf][0], S[kf][1]);
      uint32_t u1 = cvt_pk_bf16(S[kf][2], S[kf][3]);
      *(uint32_t*)(Pw + lrow * 88 + kf * 16 + 4 * lk)     = u0;
      *(uint32_t*)(Pw + lrow * 88 + kf * 16 + 4 * lk + 2) = u1;
    }

    // PV: A = V^T rows (LDS, swizzled), B = P^T
    __builtin_amdgcn_s_setprio(1);
#pragma unroll
    for (int ks = 0; ks < 2; ks++){
      s16x8 pB = *(const s16x8*)(Pw + lrow * 88 + ks * 32 + lk * 8);
#pragma unroll
      for (int f = 0; f < 4; f++){
        int row = f * 16 + lrow;
        int ch = (ks * 4 + lk) ^ (row & 7);
        s16x8 vfr = *(const s16x8*)(Vs + row * 64 + ch * 8);
        Oc[f] = mfma16(vfr, pB, Oc[f]);
      }
    }
    __builtin_amdgcn_s_setprio(0);

    // consolidated refill window
    __syncthreads();
    r1p += 64 * 64; r2p += 64 * 64;
    if (t < 31){
      const u16* Kn = Kp + (size_t)(k0 + 64) * 64;
#pragma unroll
      for (int i = 0; i < 2; i++){
        int g = wid * 2 + i;
        int row = g * 8 + (lane >> 3);
        int sch = (lane & 7) ^ (row & 7);
        gload_lds16(Kn + (size_t)row * 64 + sch * 8, Kt + g * 512);
        gload_lds16(Vp + (size_t)row * 2048 + (k0 + 64) + sch * 8, Vs + g * 512);
      }
    }
    __syncthreads();
  }

  // epilogue: Out[q][b][h*64 + d], d = f*16 + 4*lk + r
  float inv = 1.0f / l;
#pragma unroll
  for (int f = 0; f < 4; f++){
    f32x4 o = Oc[f] * inv;
    *(f32x4*)(Out + (size_t)(q0 + lrow) * 4096 + b * 1024 + h * 64 + f * 16 + 4 * lk) = o;
  }
}

extern "C" void kernel_launch(void* const* d_in, const int* in_sizes, int n_in,
                              void* d_out, int out_size, void* d_ws, size_t ws_size,
                              hipStream_t stream){
  const float* word = (const float*)d_in[0];   // [2048][4][1024]
  const float* pos  = (const float*)d_in[1];   // [2048][1024]
  const float* bq   = (const float*)d_in[2];   // [16][64]
  const float* bk   = (const float*)d_in[3];   // [16][64]
  const float* Wqkv = (const float*)d_in[4];   // [1024][3072]
  const float* Wr   = (const float*)d_in[5];   // [1024][1024]
  const float* br   = (const float*)d_in[6];   // [1024]
  float* out = (float*)d_out;

  char* ws = (char*)d_ws;
  size_t off = 0;
  u16* Abf   = (u16*)(ws + off); off += (size_t)8192 * 1024 * 2;
  u16* WqkvT = (u16*)(ws + off); off += (size_t)3072 * 1024 * 2;
  u16* Pbf   = (u16*)(ws + off); off += (size_t)2048 * 1024 * 2;
  u16* WrT   = (u16*)(ws + off); off += (size_t)1024 * 1024 * 2;
  u16* Qb    = (u16*)(ws + off); off += (size_t)64 * 2048 * 64 * 2; // [bh][i][64]
  u16* Kb    = (u16*)(ws + off); off += (size_t)64 * 2048 * 64 * 2;
  u16* Vb    = (u16*)(ws + off); off += (size_t)64 * 2048 * 64 * 2;
  u16* VTb   = (u16*)(ws + off); off += (size_t)64 * 64 * 2048 * 2; // [bh][64][2048]
  u16* Rb    = (u16*)(ws + off); off += (size_t)16 * 4224 * 64 * 2; // 128 pad + 2048 + tail
  if (ws_size < off) return;

  cast_f32_bf16<<<4096, 256, 0, stream>>>(word, Abf, 1048576);
  cast_f32_bf16<<<1024, 256, 0, stream>>>(pos,  Pbf, 262144);
  tcast<<<dim3(96, 32), 256, 0, stream>>>(Wqkv, WqkvT, 1024, 3072);
  tcast<<<dim3(32, 32), 256, 0, stream>>>(Wr,   WrT,   1024, 1024);
  gemm_bt<<<dim3(24, 64), 256, 0, stream>>>(Abf, WqkvT, 0, Qb, Kb, Vb, nullptr, nullptr);
  gemm_bt<<<dim3(8, 16),  256, 0, stream>>>(Pbf, WrT, 1, nullptr, nullptr, nullptr,
                                            Rb + (size_t)128 * 64, br);
  transpose_v<<<dim3(32, 64), 256, 0, stream>>>(Vb, VTb);
  attn17_kernel<<<2048, 256, 0, stream>>>(Qb, Kb, VTb, Rb, bq, bk, out);
}

// Round 19
// 459.906 us; speedup vs baseline: 1.0201x; 1.0201x over previous
//
#include <hip/hip_runtime.h>
#include <stdint.h>

typedef unsigned short u16;
typedef __attribute__((ext_vector_type(8))) short  s16x8;
typedef __attribute__((ext_vector_type(8))) __bf16 b16x8;
typedef __attribute__((ext_vector_type(4))) float  f32x4;

__device__ __forceinline__ float bf2f(u16 u){
  union { unsigned int ui; float f; } v; v.ui = ((unsigned int)u) << 16; return v.f;
}
__device__ __forceinline__ u16 f2bf(float f){
  union { float f; unsigned int ui; } v; v.f = f;
  unsigned int u = v.ui;
  u += 0x7FFFu + ((u >> 16) & 1u);      // RNE
  return (u16)(u >> 16);
}
__device__ __forceinline__ f32x4 mfma16(s16x8 a, s16x8 b, f32x4 c){
  return __builtin_amdgcn_mfma_f32_16x16x32_bf16(
      __builtin_bit_cast(b16x8, a), __builtin_bit_cast(b16x8, b), c, 0, 0, 0);
}
__device__ __forceinline__ void gload_lds16(const u16* g, u16* l){
  __builtin_amdgcn_global_load_lds(
      (const __attribute__((address_space(1))) unsigned int*)(g),
      (__attribute__((address_space(3))) unsigned int*)(l), 16, 0, 0);
}
__device__ __forceinline__ uint32_t cvt_pk_bf16(float lo, float hi){
  uint32_t r;
  asm("v_cvt_pk_bf16_f32 %0, %1, %2" : "=v"(r) : "v"(lo), "v"(hi));
  return r;
}

// ---------------- elementwise cast f32 -> bf16 (8 elems/thread) ----------------
__global__ __launch_bounds__(256) void cast_f32_bf16(const float* __restrict__ in,
                                                     u16* __restrict__ out, int n8){
  int i = blockIdx.x * 256 + threadIdx.x;
  if (i >= n8) return;
  const f32x4* p = (const f32x4*)(in + (size_t)i * 8);
  f32x4 a = p[0], c = p[1];
  s16x8 o;
#pragma unroll
  for (int j = 0; j < 4; j++){ o[j] = (short)f2bf(a[j]); o[j+4] = (short)f2bf(c[j]); }
  *(s16x8*)(out + (size_t)i * 8) = o;
}

// ---------------- transpose + cast: in f32 [R][C] -> out bf16 [C][R] ----------------
__global__ __launch_bounds__(256) void tcast(const float* __restrict__ in,
                                             u16* __restrict__ out, int R, int C){
  __shared__ float tile[32][33];
  int c0 = blockIdx.x * 32, r0 = blockIdx.y * 32;
  int tc = threadIdx.x & 31, tr = threadIdx.x >> 5;
#pragma unroll
  for (int p = 0; p < 4; p++)
    tile[tr + 8*p][tc] = in[(size_t)(r0 + tr + 8*p) * C + c0 + tc];
  __syncthreads();
  int rr = threadIdx.x & 31, cc = threadIdx.x >> 5;
#pragma unroll
  for (int p = 0; p < 4; p++)
    out[(size_t)(c0 + cc + 8*p) * R + r0 + rr] = f2bf(tile[rr][cc + 8*p]);
}

// ---------------- GEMM: C[M,N] = A[M,K=1024] * Bt[N,K=1024]^T (bf16 MFMA) ----------------
// mode 0: n<1024 -> Q; <2048 -> K; else V   ([bh][i][64])
// mode 1: + b_r -> R rows at stride 4224 (caller pre-offsets base past 128-row pad)
__global__ __launch_bounds__(256) void gemm_bt(const u16* __restrict__ A,
                                               const u16* __restrict__ Bt,
                                               int mode,
                                               u16* __restrict__ Qo, u16* __restrict__ Ko,
                                               u16* __restrict__ Vo, u16* __restrict__ Ro,
                                               const float* __restrict__ brp){
  __shared__ __align__(16) u16 lsA[2][128 * 32];
  __shared__ __align__(16) u16 lsB[2][128 * 32];
  int m0 = blockIdx.y * 128, n0 = blockIdx.x * 128;
  int t = threadIdx.x, wid = t >> 6, lane = t & 63;
  int lrow = lane & 15, lk = lane >> 4;
  int wr = wid >> 1, wc = wid & 1;

  f32x4 acc[4][4];
#pragma unroll
  for (int i = 0; i < 4; i++)
#pragma unroll
    for (int j = 0; j < 4; j++) acc[i][j] = (f32x4){0.f, 0.f, 0.f, 0.f};

  const u16* Ab = A  + (size_t)m0 * 1024;
  const u16* Bb = Bt + (size_t)n0 * 1024;

  s16x8 ra[2], rb[2];
#pragma unroll
  for (int p = 0; p < 2; p++){
    int c = p * 256 + t;
    ra[p] = *(const s16x8*)(Ab + (size_t)(c >> 2) * 1024 + (c & 3) * 8);
    rb[p] = *(const s16x8*)(Bb + (size_t)(c >> 2) * 1024 + (c & 3) * 8);
  }

  for (int kt = 0; kt < 32; kt++){
    int buf = kt & 1;
#pragma unroll
    for (int p = 0; p < 2; p++){
      int c = p * 256 + t;
      *(s16x8*)(lsA[buf] + (size_t)c * 8) = ra[p];
      *(s16x8*)(lsB[buf] + (size_t)c * 8) = rb[p];
    }
    __syncthreads();
    if (kt < 31){
      int k0 = (kt + 1) * 32;
#pragma unroll
      for (int p = 0; p < 2; p++){
        int c = p * 256 + t;
        ra[p] = *(const s16x8*)(Ab + (size_t)(c >> 2) * 1024 + k0 + (c & 3) * 8);
        rb[p] = *(const s16x8*)(Bb + (size_t)(c >> 2) * 1024 + k0 + (c & 3) * 8);
      }
    }
    s16x8 af[4], bfr[4];
#pragma unroll
    for (int i = 0; i < 4; i++)
      af[i] = *(const s16x8*)(lsA[buf] + (wr * 64 + i * 16 + lrow) * 32 + lk * 8);
#pragma unroll
    for (int j = 0; j < 4; j++)
      bfr[j] = *(const s16x8*)(lsB[buf] + (wc * 64 + j * 16 + lrow) * 32 + lk * 8);
#pragma unroll
    for (int i = 0; i < 4; i++)
#pragma unroll
      for (int j = 0; j < 4; j++)
        acc[i][j] = mfma16(af[i], bfr[j], acc[i][j]);
    __syncthreads();
  }

#pragma unroll
  for (int i = 0; i < 4; i++)
#pragma unroll
    for (int j = 0; j < 4; j++){
      int mbase = m0 + wr * 64 + i * 16 + lk * 4;
      int ncol  = n0 + wc * 64 + j * 16 + lrow;
#pragma unroll
      for (int r = 0; r < 4; r++){
        int m = mbase + r;
        float val = acc[i][j][r];
        if (mode == 0){
          int sel = ncol >> 10;
          int hd = ncol & 1023;
          int h = hd >> 6, dh = hd & 63;
          int b = m & 3, iq = m >> 2;
          size_t o = ((size_t)(b * 16 + h) * 2048 + iq) * 64 + dh;
          u16 vb = f2bf(val);
          if (sel == 0) Qo[o] = vb; else if (sel == 1) Ko[o] = vb; else Vo[o] = vb;
        } else {
          int h = ncol >> 6, dh = ncol & 63;
          Ro[((size_t)h * 4224 + m) * 64 + dh] = f2bf(val + brp[ncol]);
        }
      }
    }
}

// ---------------- V [bh][2048][64] -> VT [bh][64][2048] (bf16) ----------------
__global__ __launch_bounds__(256) void transpose_v(const u16* __restrict__ V,
                                                   u16* __restrict__ VT){
  __shared__ u16 tile[64][65];
  int bh = blockIdx.y, i0 = blockIdx.x * 64;
  const u16* src = V + ((size_t)bh * 2048 + i0) * 64;
  int t = threadIdx.x;
#pragma unroll
  for (int p = 0; p < 2; p++){
    int idx = (p * 256 + t) * 8;
    int row = idx >> 6, col = idx & 63;
    s16x8 v = *(const s16x8*)(src + idx);
#pragma unroll
    for (int e = 0; e < 8; e++) tile[row][col + e] = (u16)v[e];
  }
  __syncthreads();
  u16* dst = VT + (size_t)bh * 64 * 2048 + i0;
#pragma unroll
  for (int p = 0; p < 2; p++){
    int idx = (p * 256 + t) * 8;
    int dh = idx >> 6, ii = idx & 63;
    s16x8 o;
#pragma unroll
    for (int e = 0; e < 8; e++) o[e] = (short)tile[ii + e][dh];
    *(s16x8*)(dst + (size_t)dh * 2048 + ii) = o;
  }
}

// ---------------- fused rel-shift flash attention (v16 structure, best measured) ----------------
// grid 2048 (XCD-swizzled), 256 thr = 4 waves, wave = 16 q rows, KVBLK = 64.
// LDS 37888 -> 40960 granule; x4 = 163840 -> 4 blocks/CU (occ 46%, VGPR 64).
// Rolling 2-deep R loads, single-buffer K/V with consolidated refill window.
// BDs: d<=0 -> qb0 . r[d+2047]; d==1 -> 0; d>=2 -> qb1 . r[d-2]   (d = k - q)
__global__ __launch_bounds__(256, 4) void attn16_kernel(const u16* __restrict__ Qm,
                                                        const u16* __restrict__ Km,
                                                        const u16* __restrict__ Vt,
                                                        const u16* __restrict__ Rm,
                                                        const float* __restrict__ bq,
                                                        const float* __restrict__ bk,
                                                        float* __restrict__ Out){
  __shared__ __align__(16) u16   Kt[64 * 64];
  __shared__ __align__(16) u16   Vs[64 * 64];
  __shared__ __align__(16) float Gs[4][16 * 84];   // per-wave f32 G; P (stride-88 u16) aliases

  int lin = blockIdx.x;
  int xcd = lin & 7, j = lin >> 3;
  int hb = xcd * 8 + (j >> 5);
  int bx = j & 31;
  int h = hb & 15, b = hb >> 4;

  const int wid = threadIdx.x >> 6, lane = threadIdx.x & 63;
  const int lrow = lane & 15, lk = lane >> 4;
  const int q0 = bx * 64 + wid * 16;
  const size_t bh = (size_t)b * 16 + h;
  const u16* Qp = Qm + bh * 2048 * 64;
  const u16* Kp = Km + bh * 2048 * 64;
  const u16* Vp = Vt + bh * 64 * 2048;
  const u16* Rp = Rm + ((size_t)h * 4224 + 128) * 64;   // real row 0
  float* Gw = Gs[wid];
  u16*   Pw = (u16*)Gs[wid];

  const float cs = 0.125f * 1.44269504088896f;   // (1/sqrt(64))*log2(e), folded into q frags

  s16x8 qa[2], qb0[2], qb1[2];
  {
    const float* bqp = bq + h * 64;
    const float* bkp = bk + h * 64;
    int r1 = q0 + lrow + 1; if (r1 > 2047) r1 = 2047;   // q=2047 shifted row never selected
#pragma unroll
    for (int d = 0; d < 2; d++){
      int doff = d * 32 + lk * 8;
      s16x8 raw  = *(const s16x8*)(Qp + (size_t)(q0 + lrow) * 64 + doff);
      s16x8 raw1 = *(const s16x8*)(Qp + (size_t)r1 * 64 + doff);
      s16x8 a, c0, c1;
#pragma unroll
      for (int jj = 0; jj < 8; jj++){
        float qv = bf2f((u16)raw[jj]);
        float q1 = bf2f((u16)raw1[jj]);
        a[jj]  = (short)f2bf(cs * (qv + bqp[doff + jj]));
        c0[jj] = (short)f2bf(cs * (qv + bkp[doff + jj]));
        c1[jj] = (short)f2bf(cs * (q1 + bkp[doff + jj]));
      }
      qa[d] = a; qb0[d] = c0; qb1[d] = c1;
    }
  }

  const u16* r1p = Rp + (size_t)(2032 - q0 + lrow) * 64 + lk * 8;
  const u16* r2p = r1p - (size_t)2049 * 64;

  float m = -3.0e38f, l = 0.f;
  f32x4 Oc[4];
#pragma unroll
  for (int f = 0; f < 4; f++) Oc[f] = (f32x4){0.f, 0.f, 0.f, 0.f};

  const int wbase = 15 - lrow + 4 * lk;
  const int dl0   = 4 * lk - lrow;

  // prologue: stage K+V tile 0
#pragma unroll
  for (int i = 0; i < 2; i++){
    int g = wid * 2 + i;
    int row = g * 8 + (lane >> 3);
    int sch = (lane & 7) ^ (row & 7);
    gload_lds16(Kp + (size_t)row * 64 + sch * 8, Kt + g * 512);
    gload_lds16(Vp + (size_t)row * 2048 + sch * 8, Vs + g * 512);
  }
  __syncthreads();

  for (int t = 0; t < 32; t++){
    const int k0 = t * 64;
    const int d0 = k0 - q0;
    const bool n1 = (d0 <= 15);
    const bool n2 = (d0 >= -61);
    const bool pure = (d0 <= -63) | (d0 >= 17);
    const int dlane = d0 + dl0;

    // first 2 R window rows issued early (S-phase covers their latency)
    const u16* rp = n1 ? r1p : r2p;
    s16x8 ra[2][2];
    ra[0][0] = *(const s16x8*)(rp);
    ra[0][1] = *(const s16x8*)(rp + 32);
    ra[1][0] = *(const s16x8*)(rp + 1024);
    ra[1][1] = *(const s16x8*)(rp + 1024 + 32);

    // S^T = mfma(K, qa)
    f32x4 S[4];
    __builtin_amdgcn_s_setprio(1);
#pragma unroll
    for (int kf = 0; kf < 4; kf++){
      f32x4 acc = (f32x4){0.f, 0.f, 0.f, 0.f};
#pragma unroll
      for (int d = 0; d < 2; d++){
        int row = kf * 16 + lrow;
        int ch = (d * 4 + lk) ^ (row & 7);
        s16x8 kfr = *(const s16x8*)(Kt + row * 64 + ch * 8);
        acc = mfma16(kfr, qa[d], acc);
      }
      S[kf] = acc;
    }
    __builtin_amdgcn_s_setprio(0);

    // BD primary pass: rolling 2-deep loads
    {
      const s16x8* qs = n1 ? qb0 : qb1;
#pragma unroll
      for (int wf = 0; wf < 5; wf++){
        s16x8 c0 = ra[wf & 1][0], c1 = ra[wf & 1][1];
        if (wf < 3){
          ra[wf & 1][0] = *(const s16x8*)(rp + (wf + 2) * 1024);
          ra[wf & 1][1] = *(const s16x8*)(rp + (wf + 2) * 1024 + 32);
        }
        f32x4 g = (f32x4){0.f, 0.f, 0.f, 0.f};
        g = mfma16(c0, qs[0], g);
        g = mfma16(c1, qs[1], g);
        *(f32x4*)(Gw + lrow * 84 + wf * 16 + 4 * lk) = g;
      }
      const float* gp = Gw + lrow * 84 + wbase;
      if (pure){
#pragma unroll
        for (int kf = 0; kf < 4; kf++)
#pragma unroll
          for (int r = 0; r < 4; r++) S[kf][r] += gp[kf * 16 + r];
      } else if (n1){
#pragma unroll
        for (int kf = 0; kf < 4; kf++)
#pragma unroll
          for (int r = 0; r < 4; r++){
            float g = gp[kf * 16 + r];
            S[kf][r] += (dlane + kf * 16 + r <= 0) ? g : 0.f;
          }
      } else {
#pragma unroll
        for (int kf = 0; kf < 4; kf++)
#pragma unroll
          for (int r = 0; r < 4; r++){
            float g = gp[kf * 16 + r];
            S[kf][r] += (dlane + kf * 16 + r >= 2) ? g : 0.f;
          }
      }
    }
    // BD secondary pass (near-diagonal tiles only), rolling too
    if (n1 && n2){
      ra[0][0] = *(const s16x8*)(r2p);
      ra[0][1] = *(const s16x8*)(r2p + 32);
      ra[1][0] = *(const s16x8*)(r2p + 1024);
      ra[1][1] = *(const s16x8*)(r2p + 1024 + 32);
#pragma unroll
      for (int wf = 0; wf < 5; wf++){
        s16x8 c0 = ra[wf & 1][0], c1 = ra[wf & 1][1];
        if (wf < 3){
          ra[wf & 1][0] = *(const s16x8*)(r2p + (wf + 2) * 1024);
          ra[wf & 1][1] = *(const s16x8*)(r2p + (wf + 2) * 1024 + 32);
        }
        f32x4 g = (f32x4){0.f, 0.f, 0.f, 0.f};
        g = mfma16(c0, qb1[0], g);
        g = mfma16(c1, qb1[1], g);
        *(f32x4*)(Gw + lrow * 84 + wf * 16 + 4 * lk) = g;
      }
      const float* gp = Gw + lrow * 84 + wbase;
#pragma unroll
      for (int kf = 0; kf < 4; kf++)
#pragma unroll
        for (int r = 0; r < 4; r++){
          float g = gp[kf * 16 + r];
          S[kf][r] += (dlane + kf * 16 + r >= 2) ? g : 0.f;
        }
    }

    // softmax (q lane-local; exp2 domain, defer-max, tree reductions)
    float e0 = fmaxf(fmaxf(S[0][0], S[0][1]), fmaxf(S[0][2], S[0][3]));
    float e1 = fmaxf(fmaxf(S[1][0], S[1][1]), fmaxf(S[1][2], S[1][3]));
    float e2 = fmaxf(fmaxf(S[2][0], S[2][1]), fmaxf(S[2][2], S[2][3]));
    float e3 = fmaxf(fmaxf(S[3][0], S[3][1]), fmaxf(S[3][2], S[3][3]));
    float tmax = fmaxf(fmaxf(e0, e1), fmaxf(e2, e3));
    tmax = fmaxf(tmax, __shfl_xor(tmax, 16, 64));
    tmax = fmaxf(tmax, __shfl_xor(tmax, 32, 64));
    if (tmax > m + 11.5f){
      float al = exp2f(m - tmax);
      l *= al;
#pragma unroll
      for (int f = 0; f < 4; f++) Oc[f] *= al;
      m = tmax;
    }
#pragma unroll
    for (int kf = 0; kf < 4; kf++)
#pragma unroll
      for (int r = 0; r < 4; r++)
        S[kf][r] = exp2f(S[kf][r] - m);
    float s0 = (S[0][0] + S[0][1]) + (S[0][2] + S[0][3]);
    float s1 = (S[1][0] + S[1][1]) + (S[1][2] + S[1][3]);
    float s2 = (S[2][0] + S[2][1]) + (S[2][2] + S[2][3]);
    float s3 = (S[3][0] + S[3][1]) + (S[3][2] + S[3][3]);
    float sum = (s0 + s1) + (s2 + s3);
    sum += __shfl_xor(sum, 16, 64);
    sum += __shfl_xor(sum, 32, 64);
    l += sum;

    // P pack -> LDS [q][k] stride 88 halves
#pragma unroll
    for (int kf = 0; kf < 4; kf++){
      uint32_t u0 = cvt_pk_bf16(S[kf][0], S[kf][1]);
      uint32_t u1 = cvt_pk_bf16(S[kf][2], S[kf][3]);
      *(uint32_t*)(Pw + lrow * 88 + kf * 16 + 4 * lk)     = u0;
      *(uint32_t*)(Pw + lrow * 88 + kf * 16 + 4 * lk + 2) = u1;
    }

    // PV: A = V^T rows (LDS, swizzled), B = P^T
    __builtin_amdgcn_s_setprio(1);
#pragma unroll
    for (int ks = 0; ks < 2; ks++){
      s16x8 pB = *(const s16x8*)(Pw + lrow * 88 + ks * 32 + lk * 8);
#pragma unroll
      for (int f = 0; f < 4; f++){
        int row = f * 16 + lrow;
        int ch = (ks * 4 + lk) ^ (row & 7);
        s16x8 vfr = *(const s16x8*)(Vs + row * 64 + ch * 8);
        Oc[f] = mfma16(vfr, pB, Oc[f]);
      }
    }
    __builtin_amdgcn_s_setprio(0);

    // consolidated refill window
    __syncthreads();
    r1p += 64 * 64; r2p += 64 * 64;
    if (t < 31){
      const u16* Kn = Kp + (size_t)(k0 + 64) * 64;
#pragma unroll
      for (int i = 0; i < 2; i++){
        int g = wid * 2 + i;
        int row = g * 8 + (lane >> 3);
        int sch = (lane & 7) ^ (row & 7);
        gload_lds16(Kn + (size_t)row * 64 + sch * 8, Kt + g * 512);
        gload_lds16(Vp + (size_t)row * 2048 + (k0 + 64) + sch * 8, Vs + g * 512);
      }
    }
    __syncthreads();
  }

  // epilogue: Out[q][b][h*64 + d], d = f*16 + 4*lk + r
  float inv = 1.0f / l;
#pragma unroll
  for (int f = 0; f < 4; f++){
    f32x4 o = Oc[f] * inv;
    *(f32x4*)(Out + (size_t)(q0 + lrow) * 4096 + b * 1024 + h * 64 + f * 16 + 4 * lk) = o;
  }
}

extern "C" void kernel_launch(void* const* d_in, const int* in_sizes, int n_in,
                              void* d_out, int out_size, void* d_ws, size_t ws_size,
                              hipStream_t stream){
  const float* word = (const float*)d_in[0];   // [2048][4][1024]
  const float* pos  = (const float*)d_in[1];   // [2048][1024]
  const float* bq   = (const float*)d_in[2];   // [16][64]
  const float* bk   = (const float*)d_in[3];   // [16][64]
  const float* Wqkv = (const float*)d_in[4];   // [1024][3072]
  const float* Wr   = (const float*)d_in[5];   // [1024][1024]
  const float* br   = (const float*)d_in[6];   // [1024]
  float* out = (float*)d_out;

  char* ws = (char*)d_ws;
  size_t off = 0;
  u16* Abf   = (u16*)(ws + off); off += (size_t)8192 * 1024 * 2;
  u16* WqkvT = (u16*)(ws + off); off += (size_t)3072 * 1024 * 2;
  u16* Pbf   = (u16*)(ws + off); off += (size_t)2048 * 1024 * 2;
  u16* WrT   = (u16*)(ws + off); off += (size_t)1024 * 1024 * 2;
  u16* Qb    = (u16*)(ws + off); off += (size_t)64 * 2048 * 64 * 2; // [bh][i][64]
  u16* Kb    = (u16*)(ws + off); off += (size_t)64 * 2048 * 64 * 2;
  u16* Vb    = (u16*)(ws + off); off += (size_t)64 * 2048 * 64 * 2;
  u16* VTb   = (u16*)(ws + off); off += (size_t)64 * 64 * 2048 * 2; // [bh][64][2048]
  u16* Rb    = (u16*)(ws + off); off += (size_t)16 * 4224 * 64 * 2; // 128 pad + 2048 + tail
  if (ws_size < off) return;

  cast_f32_bf16<<<4096, 256, 0, stream>>>(word, Abf, 1048576);
  cast_f32_bf16<<<1024, 256, 0, stream>>>(pos,  Pbf, 262144);
  tcast<<<dim3(96, 32), 256, 0, stream>>>(Wqkv, WqkvT, 1024, 3072);
  tcast<<<dim3(32, 32), 256, 0, stream>>>(Wr,   WrT,   1024, 1024);
  gemm_bt<<<dim3(24, 64), 256, 0, stream>>>(Abf, WqkvT, 0, Qb, Kb, Vb, nullptr, nullptr);
  gemm_bt<<<dim3(8, 16),  256, 0, stream>>>(Pbf, WrT, 1, nullptr, nullptr, nullptr,
                                            Rb + (size_t)128 * 64, br);
  transpose_v<<<dim3(32, 64), 256, 0, stream>>>(Vb, VTb);
  attn16_kernel<<<2048, 256, 0, stream>>>(Qb, Kb, VTb, Rb, bq, bk, out);
}

// Round 20
// 456.718 us; speedup vs baseline: 1.0272x; 1.0070x over previous
//
#include <hip/hip_runtime.h>
#include <stdint.h>

typedef unsigned short u16;
typedef __attribute__((ext_vector_type(8))) short  s16x8;
typedef __attribute__((ext_vector_type(8))) __bf16 b16x8;
typedef __attribute__((ext_vector_type(4))) float  f32x4;

__device__ __forceinline__ float bf2f(u16 u){
  union { unsigned int ui; float f; } v; v.ui = ((unsigned int)u) << 16; return v.f;
}
__device__ __forceinline__ u16 f2bf(float f){
  union { float f; unsigned int ui; } v; v.f = f;
  unsigned int u = v.ui;
  u += 0x7FFFu + ((u >> 16) & 1u);      // RNE
  return (u16)(u >> 16);
}
__device__ __forceinline__ f32x4 mfma16(s16x8 a, s16x8 b, f32x4 c){
  return __builtin_amdgcn_mfma_f32_16x16x32_bf16(
      __builtin_bit_cast(b16x8, a), __builtin_bit_cast(b16x8, b), c, 0, 0, 0);
}
__device__ __forceinline__ void gload_lds16(const u16* g, u16* l){
  __builtin_amdgcn_global_load_lds(
      (const __attribute__((address_space(1))) unsigned int*)(g),
      (__attribute__((address_space(3))) unsigned int*)(l), 16, 0, 0);
}
__device__ __forceinline__ uint32_t cvt_pk_bf16(float lo, float hi){
  uint32_t r;
  asm("v_cvt_pk_bf16_f32 %0, %1, %2" : "=v"(r) : "v"(lo), "v"(hi));
  return r;
}

// ---------------- merged elementwise casts: word [0,4096) + pos [4096,5120) ----------------
__global__ __launch_bounds__(256) void cast_all(const float* __restrict__ word,
                                                const float* __restrict__ pos,
                                                u16* __restrict__ Abf,
                                                u16* __restrict__ Pbf){
  int bx = blockIdx.x;
  const float* in = bx < 4096 ? word : pos;
  u16* out = bx < 4096 ? Abf : Pbf;
  int i = (bx < 4096 ? bx : bx - 4096) * 256 + threadIdx.x;
  const f32x4* p = (const f32x4*)(in + (size_t)i * 8);
  f32x4 a = p[0], c = p[1];
  s16x8 o;
#pragma unroll
  for (int j = 0; j < 4; j++){ o[j] = (short)f2bf(a[j]); o[j+4] = (short)f2bf(c[j]); }
  *(s16x8*)(out + (size_t)i * 8) = o;
}

// ---------------- merged transpose+cast: Wqkv [0,3072) + Wr [3072,4096) ----------------
// in f32 [1024][C] -> out bf16 [C][1024]
__global__ __launch_bounds__(256) void tcast_all(const float* __restrict__ Wqkv,
                                                 const float* __restrict__ Wr,
                                                 u16* __restrict__ WqkvT,
                                                 u16* __restrict__ WrT){
  __shared__ float tile[32][33];
  int bx = blockIdx.x;
  const float* in; u16* out; int C, c0, r0;
  if (bx < 3072){
    in = Wqkv; out = WqkvT; C = 3072;
    c0 = (bx % 96) * 32; r0 = (bx / 96) * 32;
  } else {
    int lin = bx - 3072;
    in = Wr; out = WrT; C = 1024;
    c0 = (lin % 32) * 32; r0 = (lin / 32) * 32;
  }
  int tc = threadIdx.x & 31, tr = threadIdx.x >> 5;
#pragma unroll
  for (int p = 0; p < 4; p++)
    tile[tr + 8*p][tc] = in[(size_t)(r0 + tr + 8*p) * C + c0 + tc];
  __syncthreads();
  int rr = threadIdx.x & 31, cc = threadIdx.x >> 5;
#pragma unroll
  for (int p = 0; p < 4; p++)
    out[(size_t)(c0 + cc + 8*p) * 1024 + r0 + rr] = f2bf(tile[rr][cc + 8*p]);
}

// ---------------- GEMM: C[M,N] = A[M,K=1024] * Bt[N,K=1024]^T (bf16 MFMA) ----------------
// mode 0: n<1024 -> Q; <2048 -> K; else V   ([bh][i][64])
// mode 1: + b_r -> R rows at stride 4224 (caller pre-offsets base past 128-row pad)
__global__ __launch_bounds__(256) void gemm_bt(const u16* __restrict__ A,
                                               const u16* __restrict__ Bt,
                                               int mode,
                                               u16* __restrict__ Qo, u16* __restrict__ Ko,
                                               u16* __restrict__ Vo, u16* __restrict__ Ro,
                                               const float* __restrict__ brp){
  __shared__ __align__(16) u16 lsA[2][128 * 32];
  __shared__ __align__(16) u16 lsB[2][128 * 32];
  int m0 = blockIdx.y * 128, n0 = blockIdx.x * 128;
  int t = threadIdx.x, wid = t >> 6, lane = t & 63;
  int lrow = lane & 15, lk = lane >> 4;
  int wr = wid >> 1, wc = wid & 1;

  f32x4 acc[4][4];
#pragma unroll
  for (int i = 0; i < 4; i++)
#pragma unroll
    for (int j = 0; j < 4; j++) acc[i][j] = (f32x4){0.f, 0.f, 0.f, 0.f};

  const u16* Ab = A  + (size_t)m0 * 1024;
  const u16* Bb = Bt + (size_t)n0 * 1024;

  s16x8 ra[2], rb[2];
#pragma unroll
  for (int p = 0; p < 2; p++){
    int c = p * 256 + t;
    ra[p] = *(const s16x8*)(Ab + (size_t)(c >> 2) * 1024 + (c & 3) * 8);
    rb[p] = *(const s16x8*)(Bb + (size_t)(c >> 2) * 1024 + (c & 3) * 8);
  }

  for (int kt = 0; kt < 32; kt++){
    int buf = kt & 1;
#pragma unroll
    for (int p = 0; p < 2; p++){
      int c = p * 256 + t;
      *(s16x8*)(lsA[buf] + (size_t)c * 8) = ra[p];
      *(s16x8*)(lsB[buf] + (size_t)c * 8) = rb[p];
    }
    __syncthreads();
    if (kt < 31){
      int k0 = (kt + 1) * 32;
#pragma unroll
      for (int p = 0; p < 2; p++){
        int c = p * 256 + t;
        ra[p] = *(const s16x8*)(Ab + (size_t)(c >> 2) * 1024 + k0 + (c & 3) * 8);
        rb[p] = *(const s16x8*)(Bb + (size_t)(c >> 2) * 1024 + k0 + (c & 3) * 8);
      }
    }
    s16x8 af[4], bfr[4];
#pragma unroll
    for (int i = 0; i < 4; i++)
      af[i] = *(const s16x8*)(lsA[buf] + (wr * 64 + i * 16 + lrow) * 32 + lk * 8);
#pragma unroll
    for (int j = 0; j < 4; j++)
      bfr[j] = *(const s16x8*)(lsB[buf] + (wc * 64 + j * 16 + lrow) * 32 + lk * 8);
#pragma unroll
    for (int i = 0; i < 4; i++)
#pragma unroll
      for (int j = 0; j < 4; j++)
        acc[i][j] = mfma16(af[i], bfr[j], acc[i][j]);
    __syncthreads();
  }

#pragma unroll
  for (int i = 0; i < 4; i++)
#pragma unroll
    for (int j = 0; j < 4; j++){
      int mbase = m0 + wr * 64 + i * 16 + lk * 4;
      int ncol  = n0 + wc * 64 + j * 16 + lrow;
#pragma unroll
      for (int r = 0; r < 4; r++){
        int m = mbase + r;
        float val = acc[i][j][r];
        if (mode == 0){
          int sel = ncol >> 10;
          int hd = ncol & 1023;
          int h = hd >> 6, dh = hd & 63;
          int b = m & 3, iq = m >> 2;
          size_t o = ((size_t)(b * 16 + h) * 2048 + iq) * 64 + dh;
          u16 vb = f2bf(val);
          if (sel == 0) Qo[o] = vb; else if (sel == 1) Ko[o] = vb; else Vo[o] = vb;
        } else {
          int h = ncol >> 6, dh = ncol & 63;
          Ro[((size_t)h * 4224 + m) * 64 + dh] = f2bf(val + brp[ncol]);
        }
      }
    }
}

// ---------------- V [bh][2048][64] -> VT [bh][64][2048] (bf16) ----------------
__global__ __launch_bounds__(256) void transpose_v(const u16* __restrict__ V,
                                                   u16* __restrict__ VT){
  __shared__ u16 tile[64][65];
  int bh = blockIdx.y, i0 = blockIdx.x * 64;
  const u16* src = V + ((size_t)bh * 2048 + i0) * 64;
  int t = threadIdx.x;
#pragma unroll
  for (int p = 0; p < 2; p++){
    int idx = (p * 256 + t) * 8;
    int row = idx >> 6, col = idx & 63;
    s16x8 v = *(const s16x8*)(src + idx);
#pragma unroll
    for (int e = 0; e < 8; e++) tile[row][col + e] = (u16)v[e];
  }
  __syncthreads();
  u16* dst = VT + (size_t)bh * 64 * 2048 + i0;
#pragma unroll
  for (int p = 0; p < 2; p++){
    int idx = (p * 256 + t) * 8;
    int dh = idx >> 6, ii = idx & 63;
    s16x8 o;
#pragma unroll
    for (int e = 0; e < 8; e++) o[e] = (short)tile[ii + e][dh];
    *(s16x8*)(dst + (size_t)dh * 2048 + ii) = o;
  }
}

// ---------------- fused rel-shift flash attention (v16 structure, best measured) ----------------
// grid 2048 (XCD-swizzled), 256 thr = 4 waves, wave = 16 q rows, KVBLK = 64.
// LDS 37888 -> 40960 granule; x4 = 163840 -> 4 blocks/CU (occ 46%, VGPR 64).
// Rolling 2-deep R loads, single-buffer K/V with consolidated refill window.
// BDs: d<=0 -> qb0 . r[d+2047]; d==1 -> 0; d>=2 -> qb1 . r[d-2]   (d = k - q)
__global__ __launch_bounds__(256, 4) void attn16_kernel(const u16* __restrict__ Qm,
                                                        const u16* __restrict__ Km,
                                                        const u16* __restrict__ Vt,
                                                        const u16* __restrict__ Rm,
                                                        const float* __restrict__ bq,
                                                        const float* __restrict__ bk,
                                                        float* __restrict__ Out){
  __shared__ __align__(16) u16   Kt[64 * 64];
  __shared__ __align__(16) u16   Vs[64 * 64];
  __shared__ __align__(16) float Gs[4][16 * 84];   // per-wave f32 G; P (stride-88 u16) aliases

  int lin = blockIdx.x;
  int xcd = lin & 7, j = lin >> 3;
  int hb = xcd * 8 + (j >> 5);
  int bx = j & 31;
  int h = hb & 15, b = hb >> 4;

  const int wid = threadIdx.x >> 6, lane = threadIdx.x & 63;
  const int lrow = lane & 15, lk = lane >> 4;
  const int q0 = bx * 64 + wid * 16;
  const size_t bh = (size_t)b * 16 + h;
  const u16* Qp = Qm + bh * 2048 * 64;
  const u16* Kp = Km + bh * 2048 * 64;
  const u16* Vp = Vt + bh * 64 * 2048;
  const u16* Rp = Rm + ((size_t)h * 4224 + 128) * 64;   // real row 0
  float* Gw = Gs[wid];
  u16*   Pw = (u16*)Gs[wid];

  const float cs = 0.125f * 1.44269504088896f;   // (1/sqrt(64))*log2(e), folded into q frags

  s16x8 qa[2], qb0[2], qb1[2];
  {
    const float* bqp = bq + h * 64;
    const float* bkp = bk + h * 64;
    int r1 = q0 + lrow + 1; if (r1 > 2047) r1 = 2047;   // q=2047 shifted row never selected
#pragma unroll
    for (int d = 0; d < 2; d++){
      int doff = d * 32 + lk * 8;
      s16x8 raw  = *(const s16x8*)(Qp + (size_t)(q0 + lrow) * 64 + doff);
      s16x8 raw1 = *(const s16x8*)(Qp + (size_t)r1 * 64 + doff);
      s16x8 a, c0, c1;
#pragma unroll
      for (int jj = 0; jj < 8; jj++){
        float qv = bf2f((u16)raw[jj]);
        float q1 = bf2f((u16)raw1[jj]);
        a[jj]  = (short)f2bf(cs * (qv + bqp[doff + jj]));
        c0[jj] = (short)f2bf(cs * (qv + bkp[doff + jj]));
        c1[jj] = (short)f2bf(cs * (q1 + bkp[doff + jj]));
      }
      qa[d] = a; qb0[d] = c0; qb1[d] = c1;
    }
  }

  const u16* r1p = Rp + (size_t)(2032 - q0 + lrow) * 64 + lk * 8;
  const u16* r2p = r1p - (size_t)2049 * 64;

  float m = -3.0e38f, l = 0.f;
  f32x4 Oc[4];
#pragma unroll
  for (int f = 0; f < 4; f++) Oc[f] = (f32x4){0.f, 0.f, 0.f, 0.f};

  const int wbase = 15 - lrow + 4 * lk;
  const int dl0   = 4 * lk - lrow;

  // prologue: stage K+V tile 0
#pragma unroll
  for (int i = 0; i < 2; i++){
    int g = wid * 2 + i;
    int row = g * 8 + (lane >> 3);
    int sch = (lane & 7) ^ (row & 7);
    gload_lds16(Kp + (size_t)row * 64 + sch * 8, Kt + g * 512);
    gload_lds16(Vp + (size_t)row * 2048 + sch * 8, Vs + g * 512);
  }
  __syncthreads();

  for (int t = 0; t < 32; t++){
    const int k0 = t * 64;
    const int d0 = k0 - q0;
    const bool n1 = (d0 <= 15);
    const bool n2 = (d0 >= -61);
    const bool pure = (d0 <= -63) | (d0 >= 17);
    const int dlane = d0 + dl0;

    // first 2 R window rows issued early (S-phase covers their latency)
    const u16* rp = n1 ? r1p : r2p;
    s16x8 ra[2][2];
    ra[0][0] = *(const s16x8*)(rp);
    ra[0][1] = *(const s16x8*)(rp + 32);
    ra[1][0] = *(const s16x8*)(rp + 1024);
    ra[1][1] = *(const s16x8*)(rp + 1024 + 32);

    // S^T = mfma(K, qa)
    f32x4 S[4];
    __builtin_amdgcn_s_setprio(1);
#pragma unroll
    for (int kf = 0; kf < 4; kf++){
      f32x4 acc = (f32x4){0.f, 0.f, 0.f, 0.f};
#pragma unroll
      for (int d = 0; d < 2; d++){
        int row = kf * 16 + lrow;
        int ch = (d * 4 + lk) ^ (row & 7);
        s16x8 kfr = *(const s16x8*)(Kt + row * 64 + ch * 8);
        acc = mfma16(kfr, qa[d], acc);
      }
      S[kf] = acc;
    }
    __builtin_amdgcn_s_setprio(0);

    // BD primary pass: rolling 2-deep loads
    {
      const s16x8* qs = n1 ? qb0 : qb1;
#pragma unroll
      for (int wf = 0; wf < 5; wf++){
        s16x8 c0 = ra[wf & 1][0], c1 = ra[wf & 1][1];
        if (wf < 3){
          ra[wf & 1][0] = *(const s16x8*)(rp + (wf + 2) * 1024);
          ra[wf & 1][1] = *(const s16x8*)(rp + (wf + 2) * 1024 + 32);
        }
        f32x4 g = (f32x4){0.f, 0.f, 0.f, 0.f};
        g = mfma16(c0, qs[0], g);
        g = mfma16(c1, qs[1], g);
        *(f32x4*)(Gw + lrow * 84 + wf * 16 + 4 * lk) = g;
      }
      const float* gp = Gw + lrow * 84 + wbase;
      if (pure){
#pragma unroll
        for (int kf = 0; kf < 4; kf++)
#pragma unroll
          for (int r = 0; r < 4; r++) S[kf][r] += gp[kf * 16 + r];
      } else if (n1){
#pragma unroll
        for (int kf = 0; kf < 4; kf++)
#pragma unroll
          for (int r = 0; r < 4; r++){
            float g = gp[kf * 16 + r];
            S[kf][r] += (dlane + kf * 16 + r <= 0) ? g : 0.f;
          }
      } else {
#pragma unroll
        for (int kf = 0; kf < 4; kf++)
#pragma unroll
          for (int r = 0; r < 4; r++){
            float g = gp[kf * 16 + r];
            S[kf][r] += (dlane + kf * 16 + r >= 2) ? g : 0.f;
          }
      }
    }
    // BD secondary pass (near-diagonal tiles only), rolling too
    if (n1 && n2){
      ra[0][0] = *(const s16x8*)(r2p);
      ra[0][1] = *(const s16x8*)(r2p + 32);
      ra[1][0] = *(const s16x8*)(r2p + 1024);
      ra[1][1] = *(const s16x8*)(r2p + 1024 + 32);
#pragma unroll
      for (int wf = 0; wf < 5; wf++){
        s16x8 c0 = ra[wf & 1][0], c1 = ra[wf & 1][1];
        if (wf < 3){
          ra[wf & 1][0] = *(const s16x8*)(r2p + (wf + 2) * 1024);
          ra[wf & 1][1] = *(const s16x8*)(r2p + (wf + 2) * 1024 + 32);
        }
        f32x4 g = (f32x4){0.f, 0.f, 0.f, 0.f};
        g = mfma16(c0, qb1[0], g);
        g = mfma16(c1, qb1[1], g);
        *(f32x4*)(Gw + lrow * 84 + wf * 16 + 4 * lk) = g;
      }
      const float* gp = Gw + lrow * 84 + wbase;
#pragma unroll
      for (int kf = 0; kf < 4; kf++)
#pragma unroll
        for (int r = 0; r < 4; r++){
          float g = gp[kf * 16 + r];
          S[kf][r] += (dlane + kf * 16 + r >= 2) ? g : 0.f;
        }
    }

    // softmax (q lane-local; exp2 domain, defer-max, tree reductions)
    float e0 = fmaxf(fmaxf(S[0][0], S[0][1]), fmaxf(S[0][2], S[0][3]));
    float e1 = fmaxf(fmaxf(S[1][0], S[1][1]), fmaxf(S[1][2], S[1][3]));
    float e2 = fmaxf(fmaxf(S[2][0], S[2][1]), fmaxf(S[2][2], S[2][3]));
    float e3 = fmaxf(fmaxf(S[3][0], S[3][1]), fmaxf(S[3][2], S[3][3]));
    float tmax = fmaxf(fmaxf(e0, e1), fmaxf(e2, e3));
    tmax = fmaxf(tmax, __shfl_xor(tmax, 16, 64));
    tmax = fmaxf(tmax, __shfl_xor(tmax, 32, 64));
    if (tmax > m + 11.5f){
      float al = exp2f(m - tmax);
      l *= al;
#pragma unroll
      for (int f = 0; f < 4; f++) Oc[f] *= al;
      m = tmax;
    }
#pragma unroll
    for (int kf = 0; kf < 4; kf++)
#pragma unroll
      for (int r = 0; r < 4; r++)
        S[kf][r] = exp2f(S[kf][r] - m);
    float s0 = (S[0][0] + S[0][1]) + (S[0][2] + S[0][3]);
    float s1 = (S[1][0] + S[1][1]) + (S[1][2] + S[1][3]);
    float s2 = (S[2][0] + S[2][1]) + (S[2][2] + S[2][3]);
    float s3 = (S[3][0] + S[3][1]) + (S[3][2] + S[3][3]);
    float sum = (s0 + s1) + (s2 + s3);
    sum += __shfl_xor(sum, 16, 64);
    sum += __shfl_xor(sum, 32, 64);
    l += sum;

    // P pack -> LDS [q][k] stride 88 halves
#pragma unroll
    for (int kf = 0; kf < 4; kf++){
      uint32_t u0 = cvt_pk_bf16(S[kf][0], S[kf][1]);
      uint32_t u1 = cvt_pk_bf16(S[kf][2], S[kf][3]);
      *(uint32_t*)(Pw + lrow * 88 + kf * 16 + 4 * lk)     = u0;
      *(uint32_t*)(Pw + lrow * 88 + kf * 16 + 4 * lk + 2) = u1;
    }

    // PV: A = V^T rows (LDS, swizzled), B = P^T
    __builtin_amdgcn_s_setprio(1);
#pragma unroll
    for (int ks = 0; ks < 2; ks++){
      s16x8 pB = *(const s16x8*)(Pw + lrow * 88 + ks * 32 + lk * 8);
#pragma unroll
      for (int f = 0; f < 4; f++){
        int row = f * 16 + lrow;
        int ch = (ks * 4 + lk) ^ (row & 7);
        s16x8 vfr = *(const s16x8*)(Vs + row * 64 + ch * 8);
        Oc[f] = mfma16(vfr, pB, Oc[f]);
      }
    }
    __builtin_amdgcn_s_setprio(0);

    // consolidated refill window
    __syncthreads();
    r1p += 64 * 64; r2p += 64 * 64;
    if (t < 31){
      const u16* Kn = Kp + (size_t)(k0 + 64) * 64;
#pragma unroll
      for (int i = 0; i < 2; i++){
        int g = wid * 2 + i;
        int row = g * 8 + (lane >> 3);
        int sch = (lane & 7) ^ (row & 7);
        gload_lds16(Kn + (size_t)row * 64 + sch * 8, Kt + g * 512);
        gload_lds16(Vp + (size_t)row * 2048 + (k0 + 64) + sch * 8, Vs + g * 512);
      }
    }
    __syncthreads();
  }

  // epilogue: Out[q][b][h*64 + d], d = f*16 + 4*lk + r
  float inv = 1.0f / l;
#pragma unroll
  for (int f = 0; f < 4; f++){
    f32x4 o = Oc[f] * inv;
    *(f32x4*)(Out + (size_t)(q0 + lrow) * 4096 + b * 1024 + h * 64 + f * 16 + 4 * lk) = o;
  }
}

extern "C" void kernel_launch(void* const* d_in, const int* in_sizes, int n_in,
                              void* d_out, int out_size, void* d_ws, size_t ws_size,
                              hipStream_t stream){
  const float* word = (const float*)d_in[0];   // [2048][4][1024]
  const float* pos  = (const float*)d_in[1];   // [2048][1024]
  const float* bq   = (const float*)d_in[2];   // [16][64]
  const float* bk   = (const float*)d_in[3];   // [16][64]
  const float* Wqkv = (const float*)d_in[4];   // [1024][3072]
  const float* Wr   = (const float*)d_in[5];   // [1024][1024]
  const float* br   = (const float*)d_in[6];   // [1024]
  float* out = (float*)d_out;

  char* ws = (char*)d_ws;
  size_t off = 0;
  u16* Abf   = (u16*)(ws + off); off += (size_t)8192 * 1024 * 2;
  u16* WqkvT = (u16*)(ws + off); off += (size_t)3072 * 1024 * 2;
  u16* Pbf   = (u16*)(ws + off); off += (size_t)2048 * 1024 * 2;
  u16* WrT   = (u16*)(ws + off); off += (size_t)1024 * 1024 * 2;
  u16* Qb    = (u16*)(ws + off); off += (size_t)64 * 2048 * 64 * 2; // [bh][i][64]
  u16* Kb    = (u16*)(ws + off); off += (size_t)64 * 2048 * 64 * 2;
  u16* Vb    = (u16*)(ws + off); off += (size_t)64 * 2048 * 64 * 2;
  u16* VTb   = (u16*)(ws + off); off += (size_t)64 * 64 * 2048 * 2; // [bh][64][2048]
  u16* Rb    = (u16*)(ws + off); off += (size_t)16 * 4224 * 64 * 2; // 128 pad + 2048 + tail
  if (ws_size < off) return;

  cast_all<<<5120, 256, 0, stream>>>(word, pos, Abf, Pbf);
  tcast_all<<<4096, 256, 0, stream>>>(Wqkv, Wr, WqkvT, WrT);
  gemm_bt<<<dim3(24, 64), 256, 0, stream>>>(Abf, WqkvT, 0, Qb, Kb, Vb, nullptr, nullptr);
  gemm_bt<<<dim3(8, 16),  256, 0, stream>>>(Pbf, WrT, 1, nullptr, nullptr, nullptr,
                                            Rb + (size_t)128 * 64, br);
  transpose_v<<<dim3(32, 64), 256, 0, stream>>>(Vb, VTb);
  attn16_kernel<<<2048, 256, 0, stream>>>(Qb, Kb, VTb, Rb, bq, bk, out);
}

// Round 21
// 455.517 us; speedup vs baseline: 1.0299x; 1.0026x over previous
//
#include <hip/hip_runtime.h>
#include <stdint.h>

typedef unsigned short u16;
typedef __attribute__((ext_vector_type(8))) short  s16x8;
typedef __attribute__((ext_vector_type(8))) __bf16 b16x8;
typedef __attribute__((ext_vector_type(4))) float  f32x4;

__device__ __forceinline__ float bf2f(u16 u){
  union { unsigned int ui; float f; } v; v.ui = ((unsigned int)u) << 16; return v.f;
}
__device__ __forceinline__ u16 f2bf(float f){
  union { float f; unsigned int ui; } v; v.f = f;
  unsigned int u = v.ui;
  u += 0x7FFFu + ((u >> 16) & 1u);      // RNE
  return (u16)(u >> 16);
}
__device__ __forceinline__ f32x4 mfma16(s16x8 a, s16x8 b, f32x4 c){
  return __builtin_amdgcn_mfma_f32_16x16x32_bf16(
      __builtin_bit_cast(b16x8, a), __builtin_bit_cast(b16x8, b), c, 0, 0, 0);
}
__device__ __forceinline__ void gload_lds16(const u16* g, u16* l){
  __builtin_amdgcn_global_load_lds(
      (const __attribute__((address_space(1))) unsigned int*)(g),
      (__attribute__((address_space(3))) unsigned int*)(l), 16, 0, 0);
}
__device__ __forceinline__ uint32_t cvt_pk_bf16(float lo, float hi){
  uint32_t r;
  asm("v_cvt_pk_bf16_f32 %0, %1, %2" : "=v"(r) : "v"(lo), "v"(hi));
  return r;
}

// ---------------- merged elementwise casts: word [0,4096) + pos [4096,5120) ----------------
__global__ __launch_bounds__(256) void cast_all(const float* __restrict__ word,
                                                const float* __restrict__ pos,
                                                u16* __restrict__ Abf,
                                                u16* __restrict__ Pbf){
  int bx = blockIdx.x;
  const float* in = bx < 4096 ? word : pos;
  u16* out = bx < 4096 ? Abf : Pbf;
  int i = (bx < 4096 ? bx : bx - 4096) * 256 + threadIdx.x;
  const f32x4* p = (const f32x4*)(in + (size_t)i * 8);
  f32x4 a = p[0], c = p[1];
  s16x8 o;
#pragma unroll
  for (int j = 0; j < 4; j++){ o[j] = (short)f2bf(a[j]); o[j+4] = (short)f2bf(c[j]); }
  *(s16x8*)(out + (size_t)i * 8) = o;
}

// ---------------- merged transpose+cast: Wqkv [0,3072) + Wr [3072,4096) ----------------
// in f32 [1024][C] -> out bf16 [C][1024]
__global__ __launch_bounds__(256) void tcast_all(const float* __restrict__ Wqkv,
                                                 const float* __restrict__ Wr,
                                                 u16* __restrict__ WqkvT,
                                                 u16* __restrict__ WrT){
  __shared__ float tile[32][33];
  int bx = blockIdx.x;
  const float* in; u16* out; int C, c0, r0;
  if (bx < 3072){
    in = Wqkv; out = WqkvT; C = 3072;
    c0 = (bx % 96) * 32; r0 = (bx / 96) * 32;
  } else {
    int lin = bx - 3072;
    in = Wr; out = WrT; C = 1024;
    c0 = (lin % 32) * 32; r0 = (lin / 32) * 32;
  }
  int tc = threadIdx.x & 31, tr = threadIdx.x >> 5;
#pragma unroll
  for (int p = 0; p < 4; p++)
    tile[tr + 8*p][tc] = in[(size_t)(r0 + tr + 8*p) * C + c0 + tc];
  __syncthreads();
  int rr = threadIdx.x & 31, cc = threadIdx.x >> 5;
#pragma unroll
  for (int p = 0; p < 4; p++)
    out[(size_t)(c0 + cc + 8*p) * 1024 + r0 + rr] = f2bf(tile[rr][cc + 8*p]);
}

// ---------------- GEMM: C[M,N] = A[M,K=1024] * Bt[N,K=1024]^T (bf16 MFMA) ----------------
// mode 0: n<1024 -> Q; <2048 -> K; else V   ([bh][i][64])
// mode 1: + b_r -> R rows at stride 4224 (caller pre-offsets base past 128-row pad)
__global__ __launch_bounds__(256) void gemm_bt(const u16* __restrict__ A,
                                               const u16* __restrict__ Bt,
                                               int mode,
                                               u16* __restrict__ Qo, u16* __restrict__ Ko,
                                               u16* __restrict__ Vo, u16* __restrict__ Ro,
                                               const float* __restrict__ brp){
  __shared__ __align__(16) u16 lsA[2][128 * 32];
  __shared__ __align__(16) u16 lsB[2][128 * 32];
  int m0 = blockIdx.y * 128, n0 = blockIdx.x * 128;
  int t = threadIdx.x, wid = t >> 6, lane = t & 63;
  int lrow = lane & 15, lk = lane >> 4;
  int wr = wid >> 1, wc = wid & 1;

  f32x4 acc[4][4];
#pragma unroll
  for (int i = 0; i < 4; i++)
#pragma unroll
    for (int j = 0; j < 4; j++) acc[i][j] = (f32x4){0.f, 0.f, 0.f, 0.f};

  const u16* Ab = A  + (size_t)m0 * 1024;
  const u16* Bb = Bt + (size_t)n0 * 1024;

  s16x8 ra[2], rb[2];
#pragma unroll
  for (int p = 0; p < 2; p++){
    int c = p * 256 + t;
    ra[p] = *(const s16x8*)(Ab + (size_t)(c >> 2) * 1024 + (c & 3) * 8);
    rb[p] = *(const s16x8*)(Bb + (size_t)(c >> 2) * 1024 + (c & 3) * 8);
  }

  for (int kt = 0; kt < 32; kt++){
    int buf = kt & 1;
#pragma unroll
    for (int p = 0; p < 2; p++){
      int c = p * 256 + t;
      *(s16x8*)(lsA[buf] + (size_t)c * 8) = ra[p];
      *(s16x8*)(lsB[buf] + (size_t)c * 8) = rb[p];
    }
    __syncthreads();
    if (kt < 31){
      int k0 = (kt + 1) * 32;
#pragma unroll
      for (int p = 0; p < 2; p++){
        int c = p * 256 + t;
        ra[p] = *(const s16x8*)(Ab + (size_t)(c >> 2) * 1024 + k0 + (c & 3) * 8);
        rb[p] = *(const s16x8*)(Bb + (size_t)(c >> 2) * 1024 + k0 + (c & 3) * 8);
      }
    }
    s16x8 af[4], bfr[4];
#pragma unroll
    for (int i = 0; i < 4; i++)
      af[i] = *(const s16x8*)(lsA[buf] + (wr * 64 + i * 16 + lrow) * 32 + lk * 8);
#pragma unroll
    for (int j = 0; j < 4; j++)
      bfr[j] = *(const s16x8*)(lsB[buf] + (wc * 64 + j * 16 + lrow) * 32 + lk * 8);
#pragma unroll
    for (int i = 0; i < 4; i++)
#pragma unroll
      for (int j = 0; j < 4; j++)
        acc[i][j] = mfma16(af[i], bfr[j], acc[i][j]);
    __syncthreads();
  }

#pragma unroll
  for (int i = 0; i < 4; i++)
#pragma unroll
    for (int j = 0; j < 4; j++){
      int mbase = m0 + wr * 64 + i * 16 + lk * 4;
      int ncol  = n0 + wc * 64 + j * 16 + lrow;
#pragma unroll
      for (int r = 0; r < 4; r++){
        int m = mbase + r;
        float val = acc[i][j][r];
        if (mode == 0){
          int sel = ncol >> 10;
          int hd = ncol & 1023;
          int h = hd >> 6, dh = hd & 63;
          int b = m & 3, iq = m >> 2;
          size_t o = ((size_t)(b * 16 + h) * 2048 + iq) * 64 + dh;
          u16 vb = f2bf(val);
          if (sel == 0) Qo[o] = vb; else if (sel == 1) Ko[o] = vb; else Vo[o] = vb;
        } else {
          int h = ncol >> 6, dh = ncol & 63;
          Ro[((size_t)h * 4224 + m) * 64 + dh] = f2bf(val + brp[ncol]);
        }
      }
    }
}

// ---------------- V [bh][2048][64] -> VT [bh][64][2048] (bf16) ----------------
__global__ __launch_bounds__(256) void transpose_v(const u16* __restrict__ V,
                                                   u16* __restrict__ VT){
  __shared__ u16 tile[64][65];
  int bh = blockIdx.y, i0 = blockIdx.x * 64;
  const u16* src = V + ((size_t)bh * 2048 + i0) * 64;
  int t = threadIdx.x;
#pragma unroll
  for (int p = 0; p < 2; p++){
    int idx = (p * 256 + t) * 8;
    int row = idx >> 6, col = idx & 63;
    s16x8 v = *(const s16x8*)(src + idx);
#pragma unroll
    for (int e = 0; e < 8; e++) tile[row][col + e] = (u16)v[e];
  }
  __syncthreads();
  u16* dst = VT + (size_t)bh * 64 * 2048 + i0;
#pragma unroll
  for (int p = 0; p < 2; p++){
    int idx = (p * 256 + t) * 8;
    int dh = idx >> 6, ii = idx & 63;
    s16x8 o;
#pragma unroll
    for (int e = 0; e < 8; e++) o[e] = (short)tile[ii + e][dh];
    *(s16x8*)(dst + (size_t)dh * 2048 + ii) = o;
  }
}

// ---------------- fused rel-shift flash attention (v16 + deferred l-reduction) ----------------
// grid 2048 (XCD-swizzled), 256 thr = 4 waves, wave = 16 q rows, KVBLK = 64.
// LDS 37888 -> 40960 granule; x4 = 163840 -> 4 blocks/CU (occ 46%, VGPR 64).
// Rolling 2-deep R loads, single-buffer K/V with consolidated refill window.
// l kept per-lane (al rescale is wave-uniform since m is post-reduce uniform);
// cross-lane l reduce deferred to epilogue (-64 in-loop shuffle reduces).
// BDs: d<=0 -> qb0 . r[d+2047]; d==1 -> 0; d>=2 -> qb1 . r[d-2]   (d = k - q)
__global__ __launch_bounds__(256, 4) void attn21_kernel(const u16* __restrict__ Qm,
                                                        const u16* __restrict__ Km,
                                                        const u16* __restrict__ Vt,
                                                        const u16* __restrict__ Rm,
                                                        const float* __restrict__ bq,
                                                        const float* __restrict__ bk,
                                                        float* __restrict__ Out){
  __shared__ __align__(16) u16   Kt[64 * 64];
  __shared__ __align__(16) u16   Vs[64 * 64];
  __shared__ __align__(16) float Gs[4][16 * 84];   // per-wave f32 G; P (stride-88 u16) aliases

  int lin = blockIdx.x;
  int xcd = lin & 7, j = lin >> 3;
  int hb = xcd * 8 + (j >> 5);
  int bx = j & 31;
  int h = hb & 15, b = hb >> 4;

  const int wid = threadIdx.x >> 6, lane = threadIdx.x & 63;
  const int lrow = lane & 15, lk = lane >> 4;
  const int q0 = bx * 64 + wid * 16;
  const size_t bh = (size_t)b * 16 + h;
  const u16* Qp = Qm + bh * 2048 * 64;
  const u16* Kp = Km + bh * 2048 * 64;
  const u16* Vp = Vt + bh * 64 * 2048;
  const u16* Rp = Rm + ((size_t)h * 4224 + 128) * 64;   // real row 0
  float* Gw = Gs[wid];
  u16*   Pw = (u16*)Gs[wid];

  const float cs = 0.125f * 1.44269504088896f;   // (1/sqrt(64))*log2(e), folded into q frags

  s16x8 qa[2], qb0[2], qb1[2];
  {
    const float* bqp = bq + h * 64;
    const float* bkp = bk + h * 64;
    int r1 = q0 + lrow + 1; if (r1 > 2047) r1 = 2047;   // q=2047 shifted row never selected
#pragma unroll
    for (int d = 0; d < 2; d++){
      int doff = d * 32 + lk * 8;
      s16x8 raw  = *(const s16x8*)(Qp + (size_t)(q0 + lrow) * 64 + doff);
      s16x8 raw1 = *(const s16x8*)(Qp + (size_t)r1 * 64 + doff);
      s16x8 a, c0, c1;
#pragma unroll
      for (int jj = 0; jj < 8; jj++){
        float qv = bf2f((u16)raw[jj]);
        float q1 = bf2f((u16)raw1[jj]);
        a[jj]  = (short)f2bf(cs * (qv + bqp[doff + jj]));
        c0[jj] = (short)f2bf(cs * (qv + bkp[doff + jj]));
        c1[jj] = (short)f2bf(cs * (q1 + bkp[doff + jj]));
      }
      qa[d] = a; qb0[d] = c0; qb1[d] = c1;
    }
  }

  const u16* r1p = Rp + (size_t)(2032 - q0 + lrow) * 64 + lk * 8;
  const u16* r2p = r1p - (size_t)2049 * 64;

  float m = -3.0e38f, l = 0.f;   // l is PER-LANE partial (reduced at epilogue)
  f32x4 Oc[4];
#pragma unroll
  for (int f = 0; f < 4; f++) Oc[f] = (f32x4){0.f, 0.f, 0.f, 0.f};

  const int wbase = 15 - lrow + 4 * lk;
  const int dl0   = 4 * lk - lrow;

  // prologue: stage K+V tile 0
#pragma unroll
  for (int i = 0; i < 2; i++){
    int g = wid * 2 + i;
    int row = g * 8 + (lane >> 3);
    int sch = (lane & 7) ^ (row & 7);
    gload_lds16(Kp + (size_t)row * 64 + sch * 8, Kt + g * 512);
    gload_lds16(Vp + (size_t)row * 2048 + sch * 8, Vs + g * 512);
  }
  __syncthreads();

  for (int t = 0; t < 32; t++){
    const int k0 = t * 64;
    const int d0 = k0 - q0;
    const bool n1 = (d0 <= 15);
    const bool n2 = (d0 >= -61);
    const bool pure = (d0 <= -63) | (d0 >= 17);
    const int dlane = d0 + dl0;

    // first 2 R window rows issued early (S-phase covers their latency)
    const u16* rp = n1 ? r1p : r2p;
    s16x8 ra[2][2];
    ra[0][0] = *(const s16x8*)(rp);
    ra[0][1] = *(const s16x8*)(rp + 32);
    ra[1][0] = *(const s16x8*)(rp + 1024);
    ra[1][1] = *(const s16x8*)(rp + 1024 + 32);

    // S^T = mfma(K, qa)
    f32x4 S[4];
    __builtin_amdgcn_s_setprio(1);
#pragma unroll
    for (int kf = 0; kf < 4; kf++){
      f32x4 acc = (f32x4){0.f, 0.f, 0.f, 0.f};
#pragma unroll
      for (int d = 0; d < 2; d++){
        int row = kf * 16 + lrow;
        int ch = (d * 4 + lk) ^ (row & 7);
        s16x8 kfr = *(const s16x8*)(Kt + row * 64 + ch * 8);
        acc = mfma16(kfr, qa[d], acc);
      }
      S[kf] = acc;
    }
    __builtin_amdgcn_s_setprio(0);

    // BD primary pass: rolling 2-deep loads
    {
      const s16x8* qs = n1 ? qb0 : qb1;
#pragma unroll
      for (int wf = 0; wf < 5; wf++){
        s16x8 c0 = ra[wf & 1][0], c1 = ra[wf & 1][1];
        if (wf < 3){
          ra[wf & 1][0] = *(const s16x8*)(rp + (wf + 2) * 1024);
          ra[wf & 1][1] = *(const s16x8*)(rp + (wf + 2) * 1024 + 32);
        }
        f32x4 g = (f32x4){0.f, 0.f, 0.f, 0.f};
        g = mfma16(c0, qs[0], g);
        g = mfma16(c1, qs[1], g);
        *(f32x4*)(Gw + lrow * 84 + wf * 16 + 4 * lk) = g;
      }
      const float* gp = Gw + lrow * 84 + wbase;
      if (pure){
#pragma unroll
        for (int kf = 0; kf < 4; kf++)
#pragma unroll
          for (int r = 0; r < 4; r++) S[kf][r] += gp[kf * 16 + r];
      } else if (n1){
#pragma unroll
        for (int kf = 0; kf < 4; kf++)
#pragma unroll
          for (int r = 0; r < 4; r++){
            float g = gp[kf * 16 + r];
            S[kf][r] += (dlane + kf * 16 + r <= 0) ? g : 0.f;
          }
      } else {
#pragma unroll
        for (int kf = 0; kf < 4; kf++)
#pragma unroll
          for (int r = 0; r < 4; r++){
            float g = gp[kf * 16 + r];
            S[kf][r] += (dlane + kf * 16 + r >= 2) ? g : 0.f;
          }
      }
    }
    // BD secondary pass (near-diagonal tiles only), rolling too
    if (n1 && n2){
      ra[0][0] = *(const s16x8*)(r2p);
      ra[0][1] = *(const s16x8*)(r2p + 32);
      ra[1][0] = *(const s16x8*)(r2p + 1024);
      ra[1][1] = *(const s16x8*)(r2p + 1024 + 32);
#pragma unroll
      for (int wf = 0; wf < 5; wf++){
        s16x8 c0 = ra[wf & 1][0], c1 = ra[wf & 1][1];
        if (wf < 3){
          ra[wf & 1][0] = *(const s16x8*)(r2p + (wf + 2) * 1024);
          ra[wf & 1][1] = *(const s16x8*)(r2p + (wf + 2) * 1024 + 32);
        }
        f32x4 g = (f32x4){0.f, 0.f, 0.f, 0.f};
        g = mfma16(c0, qb1[0], g);
        g = mfma16(c1, qb1[1], g);
        *(f32x4*)(Gw + lrow * 84 + wf * 16 + 4 * lk) = g;
      }
      const float* gp = Gw + lrow * 84 + wbase;
#pragma unroll
      for (int kf = 0; kf < 4; kf++)
#pragma unroll
        for (int r = 0; r < 4; r++){
          float g = gp[kf * 16 + r];
          S[kf][r] += (dlane + kf * 16 + r >= 2) ? g : 0.f;
        }
    }

    // softmax (q lane-local; exp2 domain, defer-max, tree reductions; l per-lane)
    float e0 = fmaxf(fmaxf(S[0][0], S[0][1]), fmaxf(S[0][2], S[0][3]));
    float e1 = fmaxf(fmaxf(S[1][0], S[1][1]), fmaxf(S[1][2], S[1][3]));
    float e2 = fmaxf(fmaxf(S[2][0], S[2][1]), fmaxf(S[2][2], S[2][3]));
    float e3 = fmaxf(fmaxf(S[3][0], S[3][1]), fmaxf(S[3][2], S[3][3]));
    float tmax = fmaxf(fmaxf(e0, e1), fmaxf(e2, e3));
    tmax = fmaxf(tmax, __shfl_xor(tmax, 16, 64));
    tmax = fmaxf(tmax, __shfl_xor(tmax, 32, 64));   // m uniform across the q-row's 4 lanes
    if (tmax > m + 11.5f){
      float al = exp2f(m - tmax);                   // uniform -> per-lane l scaling is consistent
      l *= al;
#pragma unroll
      for (int f = 0; f < 4; f++) Oc[f] *= al;
      m = tmax;
    }
#pragma unroll
    for (int kf = 0; kf < 4; kf++)
#pragma unroll
      for (int r = 0; r < 4; r++)
        S[kf][r] = exp2f(S[kf][r] - m);
    float s0 = (S[0][0] + S[0][1]) + (S[0][2] + S[0][3]);
    float s1 = (S[1][0] + S[1][1]) + (S[1][2] + S[1][3]);
    float s2 = (S[2][0] + S[2][1]) + (S[2][2] + S[2][3]);
    float s3 = (S[3][0] + S[3][1]) + (S[3][2] + S[3][3]);
    l += (s0 + s1) + (s2 + s3);                     // per-lane partial; reduced at epilogue

    // P pack -> LDS [q][k] stride 88 halves
#pragma unroll
    for (int kf = 0; kf < 4; kf++){
      uint32_t u0 = cvt_pk_bf16(S[kf][0], S[kf][1]);
      uint32_t u1 = cvt_pk_bf16(S[kf][2], S[kf][3]);
      *(uint32_t*)(Pw + lrow * 88 + kf * 16 + 4 * lk)     = u0;
      *(uint32_t*)(Pw + lrow * 88 + kf * 16 + 4 * lk + 2) = u1;
    }

    // PV: A = V^T rows (LDS, swizzled), B = P^T
    __builtin_amdgcn_s_setprio(1);
#pragma unroll
    for (int ks = 0; ks < 2; ks++){
      s16x8 pB = *(const s16x8*)(Pw + lrow * 88 + ks * 32 + lk * 8);
#pragma unroll
      for (int f = 0; f < 4; f++){
        int row = f * 16 + lrow;
        int ch = (ks * 4 + lk) ^ (row & 7);
        s16x8 vfr = *(const s16x8*)(Vs + row * 64 + ch * 8);
        Oc[f] = mfma16(vfr, pB, Oc[f]);
      }
    }
    __builtin_amdgcn_s_setprio(0);

    // consolidated refill window
    __syncthreads();
    r1p += 64 * 64; r2p += 64 * 64;
    if (t < 31){
      const u16* Kn = Kp + (size_t)(k0 + 64) * 64;
#pragma unroll
      for (int i = 0; i < 2; i++){
        int g = wid * 2 + i;
        int row = g * 8 + (lane >> 3);
        int sch = (lane & 7) ^ (row & 7);
        gload_lds16(Kn + (size_t)row * 64 + sch * 8, Kt + g * 512);
        gload_lds16(Vp + (size_t)row * 2048 + (k0 + 64) + sch * 8, Vs + g * 512);
      }
    }
    __syncthreads();
  }

  // epilogue: reduce per-lane l across the q-row's 4 lanes, then store
  l += __shfl_xor(l, 16, 64);
  l += __shfl_xor(l, 32, 64);
  float inv = 1.0f / l;
#pragma unroll
  for (int f = 0; f < 4; f++){
    f32x4 o = Oc[f] * inv;
    *(f32x4*)(Out + (size_t)(q0 + lrow) * 4096 + b * 1024 + h * 64 + f * 16 + 4 * lk) = o;
  }
}

extern "C" void kernel_launch(void* const* d_in, const int* in_sizes, int n_in,
                              void* d_out, int out_size, void* d_ws, size_t ws_size,
                              hipStream_t stream){
  const float* word = (const float*)d_in[0];   // [2048][4][1024]
  const float* pos  = (const float*)d_in[1];   // [2048][1024]
  const float* bq   = (const float*)d_in[2];   // [16][64]
  const float* bk   = (const float*)d_in[3];   // [16][64]
  const float* Wqkv = (const float*)d_in[4];   // [1024][3072]
  const float* Wr   = (const float*)d_in[5];   // [1024][1024]
  const float* br   = (const float*)d_in[6];   // [1024]
  float* out = (float*)d_out;

  char* ws = (char*)d_ws;
  size_t off = 0;
  u16* Abf   = (u16*)(ws + off); off += (size_t)8192 * 1024 * 2;
  u16* WqkvT = (u16*)(ws + off); off += (size_t)3072 * 1024 * 2;
  u16* Pbf   = (u16*)(ws + off); off += (size_t)2048 * 1024 * 2;
  u16* WrT   = (u16*)(ws + off); off += (size_t)1024 * 1024 * 2;
  u16* Qb    = (u16*)(ws + off); off += (size_t)64 * 2048 * 64 * 2; // [bh][i][64]
  u16* Kb    = (u16*)(ws + off); off += (size_t)64 * 2048 * 64 * 2;
  u16* Vb    = (u16*)(ws + off); off += (size_t)64 * 2048 * 64 * 2;
  u16* VTb   = (u16*)(ws + off); off += (size_t)64 * 64 * 2048 * 2; // [bh][64][2048]
  u16* Rb    = (u16*)(ws + off); off += (size_t)16 * 4224 * 64 * 2; // 128 pad + 2048 + tail
  if (ws_size < off) return;

  cast_all<<<5120, 256, 0, stream>>>(word, pos, Abf, Pbf);
  tcast_all<<<4096, 256, 0, stream>>>(Wqkv, Wr, WqkvT, WrT);
  gemm_bt<<<dim3(24, 64), 256, 0, stream>>>(Abf, WqkvT, 0, Qb, Kb, Vb, nullptr, nullptr);
  gemm_bt<<<dim3(8, 16),  256, 0, stream>>>(Pbf, WrT, 1, nullptr, nullptr, nullptr,
                                            Rb + (size_t)128 * 64, br);
  transpose_v<<<dim3(32, 64), 256, 0, stream>>>(Vb, VTb);
  attn21_kernel<<<2048, 256, 0, stream>>>(Qb, Kb, VTb, Rb, bq, bk, out);
}